// Round 1
// baseline (675.555 us; speedup 1.0000x reference)
//
#include <hip/hip_runtime.h>
#include <hip/hip_bf16.h>
#include <math.h>

// Problem constants
#define BB 16
#define HH 512
#define LL 4096
#define NFFT 8192
#define LAM 0.001f

typedef __attribute__((ext_vector_type(8))) short short8;
typedef __attribute__((ext_vector_type(4))) float floatx4;

__device__ __forceinline__ void cmulf(float ar, float ai, float br, float bi,
                                      float& cr, float& ci) {
  cr = ar * br - ai * bi;
  ci = ar * bi + ai * br;
}

// -------- forward DIF FFT, N=8192, 256 threads, in-place on LDS re/im ------
// 6 radix-4 stages (len = 8192,2048,512,128,32,8) + 1 radix-2 stage (len=2).
// Output left in digit-reversed ("scrambled") order - fine for convolution.
__device__ void fft8192_fwd(float* re, float* im, int tid) {
  for (int lq = 11; lq >= 1; lq -= 2) {
    const int q = 1 << lq;
    const float angs = -6.283185307179586f / (float)(q << 2);
    for (int it = 0; it < 8; ++it) {
      const int t = tid + (it << 8);
      const int g = t >> lq;
      const int j = t & (q - 1);
      const int base = (g << (lq + 2)) + j;
      float ar = re[base],         ai = im[base];
      float br = re[base + q],     bi = im[base + q];
      float cr = re[base + 2 * q], ci = im[base + 2 * q];
      float dr = re[base + 3 * q], di = im[base + 3 * q];
      float t0r = ar + cr, t0i = ai + ci;
      float t1r = ar - cr, t1i = ai - ci;
      float t2r = br + dr, t2i = bi + di;
      float t3r = br - dr, t3i = bi - di;
      float w1r, w1i;
      __sincosf(angs * (float)j, &w1i, &w1r);  // w1 = exp(-2*pi*i*j/len)
      float w2r, w2i; cmulf(w1r, w1i, w1r, w1i, w2r, w2i);
      float w3r, w3i; cmulf(w1r, w1i, w2r, w2i, w3r, w3i);
      // y0 = t0 + t2
      re[base] = t0r + t2r; im[base] = t0i + t2i;
      // y1 = (t1 - i*t3) * w1
      float y1r, y1i; cmulf(t1r + t3i, t1i - t3r, w1r, w1i, y1r, y1i);
      re[base + q] = y1r; im[base + q] = y1i;
      // y2 = (t0 - t2) * w2
      float y2r, y2i; cmulf(t0r - t2r, t0i - t2i, w2r, w2i, y2r, y2i);
      re[base + 2 * q] = y2r; im[base + 2 * q] = y2i;
      // y3 = (t1 + i*t3) * w3
      float y3r, y3i; cmulf(t1r - t3i, t1i + t3r, w3r, w3i, y3r, y3i);
      re[base + 3 * q] = y3r; im[base + 3 * q] = y3i;
    }
    __syncthreads();
  }
  // radix-2, len=2, no twiddle
  for (int it = 0; it < 16; ++it) {
    const int t = tid + (it << 8);
    const int i0 = t << 1;
    float ar = re[i0], ai = im[i0], br = re[i0 + 1], bi = im[i0 + 1];
    re[i0] = ar + br;     im[i0] = ai + bi;
    re[i0 + 1] = ar - br; im[i0 + 1] = ai - bi;
  }
  __syncthreads();
}

// -------- inverse DIT radix-4 stages (len = 8,32,128,512,2048,8192) --------
// Exactly inverts fft8192_fwd's radix-4 stages (unnormalized; the radix-2
// inverse stage is fused with the spectral multiply in the conv kernel).
__device__ void fft8192_inv_r4(float* re, float* im, int tid) {
  for (int lq = 1; lq <= 11; lq += 2) {
    const int q = 1 << lq;
    const float angs = 6.283185307179586f / (float)(q << 2);
    for (int it = 0; it < 8; ++it) {
      const int t = tid + (it << 8);
      const int g = t >> lq;
      const int j = t & (q - 1);
      const int base = (g << (lq + 2)) + j;
      float v0r = re[base],         v0i = im[base];
      float a1r = re[base + q],     a1i = im[base + q];
      float a2r = re[base + 2 * q], a2i = im[base + 2 * q];
      float a3r = re[base + 3 * q], a3i = im[base + 3 * q];
      float w1r, w1i;
      __sincosf(angs * (float)j, &w1i, &w1r);  // conj twiddle
      float w2r, w2i; cmulf(w1r, w1i, w1r, w1i, w2r, w2i);
      float w3r, w3i; cmulf(w1r, w1i, w2r, w2i, w3r, w3i);
      float v1r, v1i; cmulf(a1r, a1i, w1r, w1i, v1r, v1i);
      float v2r, v2i; cmulf(a2r, a2i, w2r, w2i, v2r, v2i);
      float v3r, v3i; cmulf(a3r, a3i, w3r, w3i, v3r, v3i);
      float p0r = v0r + v2r, p0i = v0i + v2i;
      float m0r = v0r - v2r, m0i = v0i - v2i;
      float p1r = v1r + v3r, p1i = v1i + v3i;
      float m1r = v1r - v3r, m1i = v1i - v3i;
      re[base] = p0r + p1r;         im[base] = p0i + p1i;
      re[base + q] = m0r - m1i;     im[base + q] = m0i + m1r;   // m0 + i*m1
      re[base + 2 * q] = p0r - p1r; im[base + 2 * q] = p0i - p1i;
      re[base + 3 * q] = m0r + m1i; im[base + 3 * q] = m0i - m1r; // m0 - i*m1
    }
    __syncthreads();
  }
}

// -------- pass 0: Wout fp32 -> bf16 ----------------------------------------
__global__ void wconv_kernel(const float* __restrict__ W,
                             __hip_bfloat16* __restrict__ Wb) {
  int i = blockIdx.x * 256 + threadIdx.x;
  Wb[i] = __float2bfloat16(W[i]);
}

// -------- pass 1: squash kernel + scrambled spectrum (x 1/N) ---------------
__global__ __launch_bounds__(256) void kf_kernel(const float* __restrict__ kern,
                                                 float2* __restrict__ Kf) {
  __shared__ float re[NFFT];
  __shared__ float im[NFFT];
  const int tid = threadIdx.x;
  const int h = blockIdx.x;
  const float* kr = kern + (size_t)h * LL;
  for (int l = tid; l < LL; l += 256) {
    float kv = kr[l];
    float a = fabsf(kv) - LAM;
    float sq = (a > 0.f) ? ((kv > 0.f) ? a : -a) : 0.f;
    re[l] = sq * (1.0f / (float)NFFT);
    im[l] = 0.f;
    re[l + LL] = 0.f;
    im[l + LL] = 0.f;
  }
  __syncthreads();
  fft8192_fwd(re, im, tid);
  float2* out = Kf + (size_t)h * NFFT;
  for (int i = tid; i < NFFT; i += 256) out[i] = make_float2(re[i], im[i]);
}

__device__ __forceinline__ float gelu_exact(float y) {
  return 0.5f * y * (1.f + erff(y * 0.70710678118654752f));
}

// -------- pass 2: FFT conv for a (h, batch-pair), + skip + GELU -> g bf16 --
__global__ __launch_bounds__(256) void fftconv_kernel(
    const float* __restrict__ u, const float* __restrict__ D,
    const float2* __restrict__ Kf, __hip_bfloat16* __restrict__ g) {
  __shared__ float re[NFFT];
  __shared__ float im[NFFT];
  const int tid = threadIdx.x;
  const int p = blockIdx.x;   // batch pair 0..7
  const int h = blockIdx.y;   // 0..511
  const int b0 = 2 * p, b1 = 2 * p + 1;
  const float* u0 = u + ((size_t)(b0 * HH + h)) * LL;
  const float* u1 = u + ((size_t)(b1 * HH + h)) * LL;

  // load: z = u0 + i*u1, zero-pad to 8192
  for (int i = tid; i < LL / 4; i += 256) {
    float4 a = ((const float4*)u0)[i];
    float4 b = ((const float4*)u1)[i];
    ((float4*)re)[i] = a;
    ((float4*)im)[i] = b;
    ((float4*)(re + LL))[i] = make_float4(0.f, 0.f, 0.f, 0.f);
    ((float4*)(im + LL))[i] = make_float4(0.f, 0.f, 0.f, 0.f);
  }
  __syncthreads();

  fft8192_fwd(re, im, tid);

  // spectral multiply (scrambled order matches Kf) fused with the inverse
  // radix-2 stage (adjacent pairs, no twiddle)
  const float2* kf = Kf + (size_t)h * NFFT;
  for (int it = 0; it < 16; ++it) {
    const int t = tid + (it << 8);
    const int i0 = t << 1;
    float4 kk = ((const float4*)kf)[t];  // (k0.re,k0.im,k1.re,k1.im)
    float ar, ai, br, bi;
    cmulf(re[i0], im[i0], kk.x, kk.y, ar, ai);
    cmulf(re[i0 + 1], im[i0 + 1], kk.z, kk.w, br, bi);
    re[i0] = ar + br;     im[i0] = ai + bi;
    re[i0 + 1] = ar - br; im[i0 + 1] = ai - bi;
  }
  __syncthreads();

  fft8192_inv_r4(re, im, tid);

  // epilogue: skip + GELU -> bf16
  const float Dh = D[h];
  __hip_bfloat16* g0 = g + ((size_t)(b0 * HH + h)) * LL;
  __hip_bfloat16* g1 = g + ((size_t)(b1 * HH + h)) * LL;
  for (int l = tid; l < LL; l += 256) {
    float y0 = re[l] + Dh * u0[l];
    float y1 = im[l] + Dh * u1[l];
    g0[l] = __float2bfloat16(gelu_exact(y0));
    g1[l] = __float2bfloat16(gelu_exact(y1));
  }
}

// -------- pass 2.5: transpose g[b][h][l] -> g2[b][l][h] (bf16) -------------
__global__ __launch_bounds__(256) void transpose_kernel(
    const __hip_bfloat16* __restrict__ g, __hip_bfloat16* __restrict__ g2) {
  __shared__ unsigned short tile[64][72];  // 72: odd-ish stride, 16B-aligned rows
  const int lb = blockIdx.x;  // l block (64 wide), 0..63
  const int hb = blockIdx.y;  // h block, 0..7
  const int b = blockIdx.z;
  const int l0 = lb * 64, h0 = hb * 64;
  const int tid = threadIdx.x;
  const int r = tid >> 3;        // 0..31
  const int c = (tid & 7) * 8;   // 0..56
  const unsigned short* gs = (const unsigned short*)g;
  unsigned short* g2s = (unsigned short*)g2;
  for (int it = 0; it < 2; ++it) {
    int rr = r + it * 32;  // h-local row
    int4 v = *(const int4*)(gs + ((size_t)(b * HH + h0 + rr)) * LL + l0 + c);
    *(int4*)&tile[rr][c] = v;
  }
  __syncthreads();
  for (int it = 0; it < 2; ++it) {
    int rr = r + it * 32;  // l-local row
    unsigned short vals[8];
#pragma unroll
    for (int j = 0; j < 8; ++j) vals[j] = tile[c + j][rr];
    *(int4*)(g2s + ((size_t)(b * LL + l0 + rr)) * HH + h0 + c) = *(int4*)vals;
  }
}

// -------- pass 3: out[b][v][l] = silu(sum_h W[v][h]*g2[b][l][h] + bout[v]) -
// LDS-free MFMA GEMM: fragments straight from global (W and g2 are L2-hot,
// K-dim h is contiguous in both operands).
__global__ __launch_bounds__(256) void gemm_kernel(
    const __hip_bfloat16* __restrict__ Wb, const __hip_bfloat16* __restrict__ g2,
    const float* __restrict__ bout, float* __restrict__ out) {
  const int lt = blockIdx.x;  // 0..31, 128 cols of l
  const int vt = blockIdx.y;  // 0..3, 128 rows of v
  const int b = blockIdx.z;
  const int wave = threadIdx.x >> 6;
  const int ln = threadIdx.x & 63;
  const int wr = wave >> 1, wc = wave & 1;
  const int vbase = vt * 128 + wr * 64;
  const int lbase = lt * 128 + wc * 64;
  const int lane16 = ln & 15;
  const int quad = ln >> 4;

  floatx4 acc[4][4];
#pragma unroll
  for (int mi = 0; mi < 4; ++mi)
#pragma unroll
    for (int ni = 0; ni < 4; ++ni) acc[mi][ni] = (floatx4){0.f, 0.f, 0.f, 0.f};

  const unsigned short* A = (const unsigned short*)Wb;               // [512][512]
  const unsigned short* Bm = (const unsigned short*)g2 + (size_t)b * LL * HH;

  for (int k0 = 0; k0 < HH; k0 += 32) {
    const int kk = k0 + quad * 8;
    short8 af[4], bf[4];
#pragma unroll
    for (int mi = 0; mi < 4; ++mi) {
      const int m = vbase + mi * 16 + lane16;
      af[mi] = *(const short8*)(A + (size_t)m * HH + kk);
    }
#pragma unroll
    for (int ni = 0; ni < 4; ++ni) {
      const int n = lbase + ni * 16 + lane16;
      bf[ni] = *(const short8*)(Bm + (size_t)n * HH + kk);
    }
#pragma unroll
    for (int mi = 0; mi < 4; ++mi)
#pragma unroll
      for (int ni = 0; ni < 4; ++ni)
        acc[mi][ni] = __builtin_amdgcn_mfma_f32_16x16x32_bf16(af[mi], bf[ni],
                                                              acc[mi][ni], 0, 0, 0);
  }

#pragma unroll
  for (int mi = 0; mi < 4; ++mi) {
#pragma unroll
    for (int r = 0; r < 4; ++r) {
      const int m = vbase + mi * 16 + quad * 4 + r;
      const float bias = bout[m];
#pragma unroll
      for (int ni = 0; ni < 4; ++ni) {
        const int n = lbase + ni * 16 + lane16;
        float y = acc[mi][ni][r] + bias;
        y = y / (1.f + __expf(-y));  // silu
        out[((size_t)(b * HH + m)) * LL + n] = y;
      }
    }
  }
}

extern "C" void kernel_launch(void* const* d_in, const int* in_sizes, int n_in,
                              void* d_out, int out_size, void* d_ws, size_t ws_size,
                              hipStream_t stream) {
  const float* u = (const float*)d_in[0];      // (16,512,4096)
  const float* kern = (const float*)d_in[1];   // (1,512,4096)
  const float* D = (const float*)d_in[2];      // (1,512)
  const float* Wout = (const float*)d_in[3];   // (512,512)
  const float* bout = (const float*)d_in[4];   // (512,)
  float* out = (float*)d_out;                  // (16,512,4096) fp32

  char* ws = (char*)d_ws;
  const size_t KF_BYTES = (size_t)HH * NFFT * sizeof(float2);      // 33.5 MB
  const size_t G_BYTES = (size_t)BB * HH * LL * 2;                 // 67.1 MB
  float2* Kf = (float2*)ws;
  __hip_bfloat16* g = (__hip_bfloat16*)(ws + KF_BYTES);
  __hip_bfloat16* g2 = (__hip_bfloat16*)(ws + KF_BYTES + G_BYTES);
  __hip_bfloat16* Wb = (__hip_bfloat16*)(ws + KF_BYTES + 2 * G_BYTES);

  wconv_kernel<<<dim3((HH * HH) / 256), dim3(256), 0, stream>>>(Wout, Wb);
  kf_kernel<<<dim3(HH), dim3(256), 0, stream>>>(kern, Kf);
  fftconv_kernel<<<dim3(BB / 2, HH), dim3(256), 0, stream>>>(u, D, Kf, g);
  transpose_kernel<<<dim3(LL / 64, HH / 64, BB), dim3(256), 0, stream>>>(g, g2);
  gemm_kernel<<<dim3(LL / 128, HH / 128, BB), dim3(256), 0, stream>>>(Wb, g2, bout, out);
}

// Round 2
// 628.046 us; speedup vs baseline: 1.0756x; 1.0756x over previous
//
#include <hip/hip_runtime.h>
#include <hip/hip_bf16.h>
#include <math.h>

// Problem constants
#define BB 16
#define HH 512
#define LL 4096
#define NFFT 8192
#define LAM 0.001f

typedef __attribute__((ext_vector_type(8))) short short8;
typedef __attribute__((ext_vector_type(4))) float floatx4;

__device__ __forceinline__ void cmul(float ar, float ai, float br, float bi,
                                     float& cr, float& ci) {
  cr = ar * br - ai * bi;
  ci = ar * bi + ai * br;
}

// W16^e = exp(-2*pi*i*e/16), e = j*m for j,m in [0,4)
constexpr float W16C[10] = {1.f, 0.92387953f, 0.70710678f, 0.38268343f, 0.f,
                            -0.38268343f, -0.70710678f, -0.92387953f, -1.f, -0.92387953f};
constexpr float W16S[10] = {0.f, -0.38268343f, -0.70710678f, -0.92387953f, -1.f,
                            -0.92387953f, -0.70710678f, -0.38268343f, 0.f, 0.38268343f};
// W32^j = exp(-2*pi*i*j/32), j in [0,16)
constexpr float W32C[16] = {1.f, 0.98078528f, 0.92387953f, 0.83146961f, 0.70710678f,
                            0.55557023f, 0.38268343f, 0.19509032f, 0.f, -0.19509032f,
                            -0.38268343f, -0.55557023f, -0.70710678f, -0.83146961f,
                            -0.92387953f, -0.98078528f};
constexpr float W32S[16] = {0.f, -0.19509032f, -0.38268343f, -0.55557023f, -0.70710678f,
                            -0.83146961f, -0.92387953f, -0.98078528f, -1.f, -0.98078528f,
                            -0.92387953f, -0.83146961f, -0.70710678f, -0.55557023f,
                            -0.38268343f, -0.19509032f};

// ---- 16-point DIF FFT, natural-order in/out, in registers ----
__device__ __forceinline__ void fft16_f(float* xr, float* xi) {
  float yr[16], yi[16];
#pragma unroll
  for (int j = 0; j < 4; ++j) {
    float t0r = xr[j] + xr[j + 8],      t0i = xi[j] + xi[j + 8];
    float t1r = xr[j] - xr[j + 8],      t1i = xi[j] - xi[j + 8];
    float t2r = xr[j + 4] + xr[j + 12], t2i = xi[j + 4] + xi[j + 12];
    float t3r = xr[j + 4] - xr[j + 12], t3i = xi[j + 4] - xi[j + 12];
    float o0r = t0r + t2r, o0i = t0i + t2i;
    float o1r = t1r + t3i, o1i = t1i - t3r;   // t1 - i t3
    float o2r = t0r - t2r, o2i = t0i - t2i;
    float o3r = t1r - t3i, o3i = t1i + t3r;   // t1 + i t3
    yr[j] = o0r; yi[j] = o0i;
    if (j == 0) {
      yr[4] = o1r; yi[4] = o1i; yr[8] = o2r; yi[8] = o2i; yr[12] = o3r; yi[12] = o3i;
    } else {
      cmul(o1r, o1i, W16C[j], W16S[j], yr[j + 4], yi[j + 4]);
      cmul(o2r, o2i, W16C[2 * j], W16S[2 * j], yr[j + 8], yi[j + 8]);
      cmul(o3r, o3i, W16C[3 * j], W16S[3 * j], yr[j + 12], yi[j + 12]);
    }
  }
#pragma unroll
  for (int m = 0; m < 4; ++m) {
    float t0r = yr[4 * m] + yr[4 * m + 2],     t0i = yi[4 * m] + yi[4 * m + 2];
    float t1r = yr[4 * m] - yr[4 * m + 2],     t1i = yi[4 * m] - yi[4 * m + 2];
    float t2r = yr[4 * m + 1] + yr[4 * m + 3], t2i = yi[4 * m + 1] + yi[4 * m + 3];
    float t3r = yr[4 * m + 1] - yr[4 * m + 3], t3i = yi[4 * m + 1] - yi[4 * m + 3];
    xr[m] = t0r + t2r;       xi[m] = t0i + t2i;
    xr[m + 4] = t1r + t3i;   xi[m + 4] = t1i - t3r;
    xr[m + 8] = t0r - t2r;   xi[m + 8] = t0i - t2i;
    xr[m + 12] = t1r - t3i;  xi[m + 12] = t1i + t3r;
  }
}

// ---- inverse (unnormalized x16), natural-order in/out ----
__device__ __forceinline__ void ifft16_f(float* xr, float* xi) {
  float yr[16], yi[16];
#pragma unroll
  for (int m = 0; m < 4; ++m) {
    float t0r = xr[m] + xr[m + 8],      t0i = xi[m] + xi[m + 8];
    float t1r = xr[m] - xr[m + 8],      t1i = xi[m] - xi[m + 8];
    float t2r = xr[m + 4] + xr[m + 12], t2i = xi[m + 4] + xi[m + 12];
    float t3r = xr[m + 4] - xr[m + 12], t3i = xi[m + 4] - xi[m + 12];
    yr[4 * m] = t0r + t2r;     yi[4 * m] = t0i + t2i;
    yr[4 * m + 1] = t1r - t3i; yi[4 * m + 1] = t1i + t3r;  // t1 + i t3
    yr[4 * m + 2] = t0r - t2r; yi[4 * m + 2] = t0i - t2i;
    yr[4 * m + 3] = t1r + t3i; yi[4 * m + 3] = t1i - t3r;  // t1 - i t3
  }
#pragma unroll
  for (int j = 0; j < 4; ++j) {
    float v0r = yr[j], v0i = yi[j];
    float v1r, v1i, v2r, v2i, v3r, v3i;
    if (j == 0) {
      v1r = yr[4]; v1i = yi[4]; v2r = yr[8]; v2i = yi[8]; v3r = yr[12]; v3i = yi[12];
    } else {
      cmul(yr[j + 4], yi[j + 4], W16C[j], -W16S[j], v1r, v1i);
      cmul(yr[j + 8], yi[j + 8], W16C[2 * j], -W16S[2 * j], v2r, v2i);
      cmul(yr[j + 12], yi[j + 12], W16C[3 * j], -W16S[3 * j], v3r, v3i);
    }
    float t0r = v0r + v2r, t0i = v0i + v2i;
    float t1r = v0r - v2r, t1i = v0i - v2i;
    float t2r = v1r + v3r, t2i = v1i + v3i;
    float t3r = v1r - v3r, t3i = v1i - v3i;
    xr[j] = t0r + t2r;       xi[j] = t0i + t2i;
    xr[j + 4] = t1r - t3i;   xi[j + 4] = t1i + t3r;
    xr[j + 8] = t0r - t2r;   xi[j + 8] = t0i - t2i;
    xr[j + 12] = t1r + t3i;  xi[j + 12] = t1i - t3r;
  }
}

// ---- 32-point FFT, "split" output order (consistent fwd/inv), registers ----
__device__ __forceinline__ void fft32_f(float* xr, float* xi) {
#pragma unroll
  for (int j = 0; j < 16; ++j) {
    float ar = xr[j], ai = xi[j], br = xr[j + 16], bi = xi[j + 16];
    xr[j] = ar + br; xi[j] = ai + bi;
    float dr = ar - br, di = ai - bi;
    cmul(dr, di, W32C[j], W32S[j], xr[j + 16], xi[j + 16]);
  }
  fft16_f(xr, xi);
  fft16_f(xr + 16, xi + 16);
}
__device__ __forceinline__ void ifft32_f(float* xr, float* xi) {
  ifft16_f(xr, xi);
  ifft16_f(xr + 16, xi + 16);
#pragma unroll
  for (int j = 0; j < 16; ++j) {
    float zr, zi;
    cmul(xr[j + 16], xi[j + 16], W32C[j], -W32S[j], zr, zi);
    float ar = xr[j], ai = xi[j];
    xr[j] = ar + zr;      xi[j] = ai + zi;
    xr[j + 16] = ar - zr; xi[j + 16] = ai - zi;
  }
}

__device__ __forceinline__ float gelu_exact(float y) {
  return 0.5f * y * (1.f + erff(y * 0.70710678118654752f));
}

// -------- pass 0: Wout fp32 -> bf16 ----------------------------------------
__global__ void wconv_kernel(const float* __restrict__ W,
                             __hip_bfloat16* __restrict__ Wb) {
  int i = blockIdx.x * 256 + threadIdx.x;
  Wb[i] = __float2bfloat16(W[i]);
}

// -------- pass 1: squash kernel + scrambled spectrum (x 1/N) ---------------
// Network: P1 radix-16 (q=512), P2 radix-16 (q=32), P3 radix-32 in registers.
__global__ __launch_bounds__(256) void kf_kernel(const float* __restrict__ kern,
                                                 float* __restrict__ Kf) {
  __shared__ __align__(16) float sre[NFFT];
  __shared__ __align__(16) float sim[NFFT];
  const int t = threadIdx.x;
  const int h = blockIdx.x;
  const float* kr = kern + (size_t)h * LL;

  // P1
#pragma unroll
  for (int it = 0; it < 2; ++it) {
    const int j = t + it * 256;
    float xr[16], xi[16];
#pragma unroll
    for (int r = 0; r < 8; ++r) {
      float kv = kr[j + 512 * r];
      float a = fabsf(kv) - LAM;
      float sq = (a > 0.f) ? ((kv > 0.f) ? a : -a) : 0.f;
      xr[r] = sq * (1.0f / (float)NFFT);
      xi[r] = 0.f;
    }
#pragma unroll
    for (int r = 8; r < 16; ++r) { xr[r] = 0.f; xi[r] = 0.f; }
    fft16_f(xr, xi);
    float c1, s1;
    __sincosf(-6.283185307179586f * (float)j / 8192.f, &s1, &c1);
    float wr = 1.f, wi = 0.f;
#pragma unroll
    for (int m = 0; m < 16; ++m) {
      float tr, ti;
      if (m == 0) { tr = xr[0]; ti = xi[0]; }
      else cmul(xr[m], xi[m], wr, wi, tr, ti);
      sre[j + 512 * m] = tr; sim[j + 512 * m] = ti;
      float nwr, nwi; cmul(wr, wi, c1, s1, nwr, nwi); wr = nwr; wi = nwi;
    }
  }
  __syncthreads();

  // P2
#pragma unroll
  for (int it = 0; it < 2; ++it) {
    const int tt = t + it * 256;
    const int jj = tt & 31, gg = tt >> 5;
    const int base = gg * 512 + jj;
    float xr[16], xi[16];
#pragma unroll
    for (int m = 0; m < 16; ++m) { xr[m] = sre[base + 32 * m]; xi[m] = sim[base + 32 * m]; }
    fft16_f(xr, xi);
    float c1, s1;
    __sincosf(-6.283185307179586f * (float)jj / 512.f, &s1, &c1);
    float wr = 1.f, wi = 0.f;
#pragma unroll
    for (int m = 0; m < 16; ++m) {
      float tr, ti;
      if (m == 0) { tr = xr[0]; ti = xi[0]; }
      else cmul(xr[m], xi[m], wr, wi, tr, ti);
      sre[base + 32 * m] = tr; sim[base + 32 * m] = ti;
      float nwr, nwi; cmul(wr, wi, c1, s1, nwr, nwi); wr = nwr; wi = nwi;
    }
  }
  __syncthreads();

  // P3: contiguous block [32t, 32t+32) -> registers, FFT32, store interleaved
  float xr[32], xi[32];
#pragma unroll
  for (int c = 0; c < 8; ++c) {
    float4 vr = ((const float4*)sre)[8 * t + c];
    float4 vi = ((const float4*)sim)[8 * t + c];
    xr[4 * c] = vr.x; xr[4 * c + 1] = vr.y; xr[4 * c + 2] = vr.z; xr[4 * c + 3] = vr.w;
    xi[4 * c] = vi.x; xi[4 * c + 1] = vi.y; xi[4 * c + 2] = vi.z; xi[4 * c + 3] = vi.w;
  }
  fft32_f(xr, xi);
  float4* out4 = (float4*)(Kf + (size_t)h * NFFT * 2) + 16 * t;
#pragma unroll
  for (int c = 0; c < 16; ++c)
    out4[c] = make_float4(xr[2 * c], xi[2 * c], xr[2 * c + 1], xi[2 * c + 1]);
}

// -------- pass 2: FFT conv (h, batch-pair) + skip + GELU -> g bf16 ---------
__global__ __launch_bounds__(256) void fftconv_kernel(
    const float* __restrict__ u, const float* __restrict__ D,
    const float* __restrict__ Kf, __hip_bfloat16* __restrict__ g) {
  __shared__ __align__(16) float sre[NFFT];
  __shared__ __align__(16) float sim[NFFT];
  const int t = threadIdx.x;
  const int p = blockIdx.x;   // batch pair 0..7
  const int h = blockIdx.y;   // 0..511
  const int b0 = 2 * p, b1 = 2 * p + 1;
  const float* u0 = u + ((size_t)(b0 * HH + h)) * LL;
  const float* u1 = u + ((size_t)(b1 * HH + h)) * LL;

  float us0[2][8], us1[2][8];  // register stash of u for the epilogue

  // ---- P1: radix-16, q=512 (loads straight from global) ----
#pragma unroll
  for (int it = 0; it < 2; ++it) {
    const int j = t + it * 256;
    float xr[16], xi[16];
#pragma unroll
    for (int r = 0; r < 8; ++r) {
      float a = u0[j + 512 * r];
      float b = u1[j + 512 * r];
      us0[it][r] = a; us1[it][r] = b;
      xr[r] = a; xi[r] = b;
    }
#pragma unroll
    for (int r = 8; r < 16; ++r) { xr[r] = 0.f; xi[r] = 0.f; }
    fft16_f(xr, xi);
    float c1, s1;
    __sincosf(-6.283185307179586f * (float)j / 8192.f, &s1, &c1);
    float wr = 1.f, wi = 0.f;
#pragma unroll
    for (int m = 0; m < 16; ++m) {
      float tr, ti;
      if (m == 0) { tr = xr[0]; ti = xi[0]; }
      else cmul(xr[m], xi[m], wr, wi, tr, ti);
      sre[j + 512 * m] = tr; sim[j + 512 * m] = ti;
      float nwr, nwi; cmul(wr, wi, c1, s1, nwr, nwi); wr = nwr; wi = nwi;
    }
  }
  __syncthreads();

  // ---- P2: radix-16, q=32 ----
#pragma unroll
  for (int it = 0; it < 2; ++it) {
    const int tt = t + it * 256;
    const int jj = tt & 31, gg = tt >> 5;
    const int base = gg * 512 + jj;
    float xr[16], xi[16];
#pragma unroll
    for (int m = 0; m < 16; ++m) { xr[m] = sre[base + 32 * m]; xi[m] = sim[base + 32 * m]; }
    fft16_f(xr, xi);
    float c1, s1;
    __sincosf(-6.283185307179586f * (float)jj / 512.f, &s1, &c1);
    float wr = 1.f, wi = 0.f;
#pragma unroll
    for (int m = 0; m < 16; ++m) {
      float tr, ti;
      if (m == 0) { tr = xr[0]; ti = xi[0]; }
      else cmul(xr[m], xi[m], wr, wi, tr, ti);
      sre[base + 32 * m] = tr; sim[base + 32 * m] = ti;
      float nwr, nwi; cmul(wr, wi, c1, s1, nwr, nwi); wr = nwr; wi = nwi;
    }
  }
  __syncthreads();

  // ---- P3: in-register FFT32 + spectral multiply + iFFT32 ----
  {
    float xr[32], xi[32];
#pragma unroll
    for (int c = 0; c < 8; ++c) {
      float4 vr = ((const float4*)sre)[8 * t + c];
      float4 vi = ((const float4*)sim)[8 * t + c];
      xr[4 * c] = vr.x; xr[4 * c + 1] = vr.y; xr[4 * c + 2] = vr.z; xr[4 * c + 3] = vr.w;
      xi[4 * c] = vi.x; xi[4 * c + 1] = vi.y; xi[4 * c + 2] = vi.z; xi[4 * c + 3] = vi.w;
    }
    fft32_f(xr, xi);
    const float4* kf4 = (const float4*)(Kf + (size_t)h * NFFT * 2) + 16 * t;
#pragma unroll
    for (int c = 0; c < 16; ++c) {
      float4 kk = kf4[c];
      float tr, ti;
      cmul(xr[2 * c], xi[2 * c], kk.x, kk.y, tr, ti);
      xr[2 * c] = tr; xi[2 * c] = ti;
      cmul(xr[2 * c + 1], xi[2 * c + 1], kk.z, kk.w, tr, ti);
      xr[2 * c + 1] = tr; xi[2 * c + 1] = ti;
    }
    ifft32_f(xr, xi);
#pragma unroll
    for (int c = 0; c < 8; ++c) {
      ((float4*)sre)[8 * t + c] = make_float4(xr[4 * c], xr[4 * c + 1], xr[4 * c + 2], xr[4 * c + 3]);
      ((float4*)sim)[8 * t + c] = make_float4(xi[4 * c], xi[4 * c + 1], xi[4 * c + 2], xi[4 * c + 3]);
    }
  }
  __syncthreads();

  // ---- P2' ----
#pragma unroll
  for (int it = 0; it < 2; ++it) {
    const int tt = t + it * 256;
    const int jj = tt & 31, gg = tt >> 5;
    const int base = gg * 512 + jj;
    float yr[16], yi[16];
    float c1, s1;
    __sincosf(6.283185307179586f * (float)jj / 512.f, &s1, &c1);  // conj
    float wr = 1.f, wi = 0.f;
#pragma unroll
    for (int m = 0; m < 16; ++m) {
      float ar = sre[base + 32 * m], ai = sim[base + 32 * m];
      if (m == 0) { yr[0] = ar; yi[0] = ai; }
      else cmul(ar, ai, wr, wi, yr[m], yi[m]);
      float nwr, nwi; cmul(wr, wi, c1, s1, nwr, nwi); wr = nwr; wi = nwi;
    }
    ifft16_f(yr, yi);
#pragma unroll
    for (int r = 0; r < 16; ++r) { sre[base + 32 * r] = yr[r]; sim[base + 32 * r] = yi[r]; }
  }
  __syncthreads();

  // ---- P1' + epilogue (skip + GELU -> bf16), outputs straight from regs ----
  const float Dh = D[h];
  __hip_bfloat16* g0 = g + ((size_t)(b0 * HH + h)) * LL;
  __hip_bfloat16* g1 = g + ((size_t)(b1 * HH + h)) * LL;
#pragma unroll
  for (int it = 0; it < 2; ++it) {
    const int j = t + it * 256;
    float yr[16], yi[16];
    float c1, s1;
    __sincosf(6.283185307179586f * (float)j / 8192.f, &s1, &c1);  // conj
    float wr = 1.f, wi = 0.f;
#pragma unroll
    for (int m = 0; m < 16; ++m) {
      float ar = sre[j + 512 * m], ai = sim[j + 512 * m];
      if (m == 0) { yr[0] = ar; yi[0] = ai; }
      else cmul(ar, ai, wr, wi, yr[m], yi[m]);
      float nwr, nwi; cmul(wr, wi, c1, s1, nwr, nwi); wr = nwr; wi = nwi;
    }
    ifft16_f(yr, yi);
#pragma unroll
    for (int r = 0; r < 8; ++r) {
      float y0 = yr[r] + Dh * us0[it][r];
      float y1 = yi[r] + Dh * us1[it][r];
      g0[j + 512 * r] = __float2bfloat16(gelu_exact(y0));
      g1[j + 512 * r] = __float2bfloat16(gelu_exact(y1));
    }
  }
}

// -------- pass 2.5: transpose g[b][h][l] -> g2[b][l][h] (bf16) -------------
__global__ __launch_bounds__(256) void transpose_kernel(
    const __hip_bfloat16* __restrict__ g, __hip_bfloat16* __restrict__ g2) {
  __shared__ unsigned short tile[64][72];
  const int lb = blockIdx.x;
  const int hb = blockIdx.y;
  const int b = blockIdx.z;
  const int l0 = lb * 64, h0 = hb * 64;
  const int tid = threadIdx.x;
  const int r = tid >> 3;
  const int c = (tid & 7) * 8;
  const unsigned short* gs = (const unsigned short*)g;
  unsigned short* g2s = (unsigned short*)g2;
  for (int it = 0; it < 2; ++it) {
    int rr = r + it * 32;
    int4 v = *(const int4*)(gs + ((size_t)(b * HH + h0 + rr)) * LL + l0 + c);
    *(int4*)&tile[rr][c] = v;
  }
  __syncthreads();
  for (int it = 0; it < 2; ++it) {
    int rr = r + it * 32;
    unsigned short vals[8];
#pragma unroll
    for (int j = 0; j < 8; ++j) vals[j] = tile[c + j][rr];
    *(int4*)(g2s + ((size_t)(b * LL + l0 + rr)) * HH + h0 + c) = *(int4*)vals;
  }
}

// -------- pass 3: out[b][v][l] = silu(sum_h W[v][h]*g2[b][l][h] + bout[v]) -
__global__ __launch_bounds__(256) void gemm_kernel(
    const __hip_bfloat16* __restrict__ Wb, const __hip_bfloat16* __restrict__ g2,
    const float* __restrict__ bout, float* __restrict__ out) {
  const int lt = blockIdx.x;
  const int vt = blockIdx.y;
  const int b = blockIdx.z;
  const int wave = threadIdx.x >> 6;
  const int ln = threadIdx.x & 63;
  const int wr = wave >> 1, wc = wave & 1;
  const int vbase = vt * 128 + wr * 64;
  const int lbase = lt * 128 + wc * 64;
  const int lane16 = ln & 15;
  const int quad = ln >> 4;

  floatx4 acc[4][4];
#pragma unroll
  for (int mi = 0; mi < 4; ++mi)
#pragma unroll
    for (int ni = 0; ni < 4; ++ni) acc[mi][ni] = (floatx4){0.f, 0.f, 0.f, 0.f};

  const unsigned short* A = (const unsigned short*)Wb;
  const unsigned short* Bm = (const unsigned short*)g2 + (size_t)b * LL * HH;

  for (int k0 = 0; k0 < HH; k0 += 32) {
    const int kk = k0 + quad * 8;
    short8 af[4], bf[4];
#pragma unroll
    for (int mi = 0; mi < 4; ++mi) {
      const int m = vbase + mi * 16 + lane16;
      af[mi] = *(const short8*)(A + (size_t)m * HH + kk);
    }
#pragma unroll
    for (int ni = 0; ni < 4; ++ni) {
      const int n = lbase + ni * 16 + lane16;
      bf[ni] = *(const short8*)(Bm + (size_t)n * HH + kk);
    }
#pragma unroll
    for (int mi = 0; mi < 4; ++mi)
#pragma unroll
      for (int ni = 0; ni < 4; ++ni)
        acc[mi][ni] = __builtin_amdgcn_mfma_f32_16x16x32_bf16(af[mi], bf[ni],
                                                              acc[mi][ni], 0, 0, 0);
  }

#pragma unroll
  for (int mi = 0; mi < 4; ++mi) {
#pragma unroll
    for (int r = 0; r < 4; ++r) {
      const int m = vbase + mi * 16 + quad * 4 + r;
      const float bias = bout[m];
#pragma unroll
      for (int ni = 0; ni < 4; ++ni) {
        const int n = lbase + ni * 16 + lane16;
        float y = acc[mi][ni][r] + bias;
        y = y / (1.f + __expf(-y));
        out[((size_t)(b * HH + m)) * LL + n] = y;
      }
    }
  }
}

extern "C" void kernel_launch(void* const* d_in, const int* in_sizes, int n_in,
                              void* d_out, int out_size, void* d_ws, size_t ws_size,
                              hipStream_t stream) {
  const float* u = (const float*)d_in[0];
  const float* kern = (const float*)d_in[1];
  const float* D = (const float*)d_in[2];
  const float* Wout = (const float*)d_in[3];
  const float* bout = (const float*)d_in[4];
  float* out = (float*)d_out;

  char* ws = (char*)d_ws;
  const size_t KF_BYTES = (size_t)HH * NFFT * sizeof(float2);
  const size_t G_BYTES = (size_t)BB * HH * LL * 2;
  float* Kf = (float*)ws;  // interleaved (re,im) pairs, scrambled order
  __hip_bfloat16* g = (__hip_bfloat16*)(ws + KF_BYTES);
  __hip_bfloat16* g2 = (__hip_bfloat16*)(ws + KF_BYTES + G_BYTES);
  __hip_bfloat16* Wb = (__hip_bfloat16*)(ws + KF_BYTES + 2 * G_BYTES);

  wconv_kernel<<<dim3((HH * HH) / 256), dim3(256), 0, stream>>>(Wout, Wb);
  kf_kernel<<<dim3(HH), dim3(256), 0, stream>>>(kern, Kf);
  fftconv_kernel<<<dim3(BB / 2, HH), dim3(256), 0, stream>>>(u, D, Kf, g);
  transpose_kernel<<<dim3(LL / 64, HH / 64, BB), dim3(256), 0, stream>>>(g, g2);
  gemm_kernel<<<dim3(LL / 128, HH / 128, BB), dim3(256), 0, stream>>>(Wb, g2, bout, out);
}

// Round 3
// 572.248 us; speedup vs baseline: 1.1805x; 1.0975x over previous
//
#include <hip/hip_runtime.h>
#include <hip/hip_bf16.h>
#include <math.h>

// Problem constants
#define BB 16
#define HH 512
#define LL 4096
#define NFFT 8192
#define LAM 0.001f

typedef __attribute__((ext_vector_type(8))) short short8;
typedef __attribute__((ext_vector_type(4))) float floatx4;

__device__ __forceinline__ void cmul(float ar, float ai, float br, float bi,
                                     float& cr, float& ci) {
  cr = ar * br - ai * bi;
  ci = ar * bi + ai * br;
}

// W16^e = exp(-2*pi*i*e/16), e = j*m for j,m in [0,4)
constexpr float W16C[10] = {1.f, 0.92387953f, 0.70710678f, 0.38268343f, 0.f,
                            -0.38268343f, -0.70710678f, -0.92387953f, -1.f, -0.92387953f};
constexpr float W16S[10] = {0.f, -0.38268343f, -0.70710678f, -0.92387953f, -1.f,
                            -0.92387953f, -0.70710678f, -0.38268343f, 0.f, 0.38268343f};
// W32^j = exp(-2*pi*i*j/32), j in [0,16)
constexpr float W32C[16] = {1.f, 0.98078528f, 0.92387953f, 0.83146961f, 0.70710678f,
                            0.55557023f, 0.38268343f, 0.19509032f, 0.f, -0.19509032f,
                            -0.38268343f, -0.55557023f, -0.70710678f, -0.83146961f,
                            -0.92387953f, -0.98078528f};
constexpr float W32S[16] = {0.f, -0.19509032f, -0.38268343f, -0.55557023f, -0.70710678f,
                            -0.83146961f, -0.92387953f, -0.98078528f, -1.f, -0.98078528f,
                            -0.92387953f, -0.83146961f, -0.70710678f, -0.55557023f,
                            -0.38268343f, -0.19509032f};

// ---- 16-point DIF FFT, natural-order in/out, in registers ----
__device__ __forceinline__ void fft16_f(float* xr, float* xi) {
  float yr[16], yi[16];
#pragma unroll
  for (int j = 0; j < 4; ++j) {
    float t0r = xr[j] + xr[j + 8],      t0i = xi[j] + xi[j + 8];
    float t1r = xr[j] - xr[j + 8],      t1i = xi[j] - xi[j + 8];
    float t2r = xr[j + 4] + xr[j + 12], t2i = xi[j + 4] + xi[j + 12];
    float t3r = xr[j + 4] - xr[j + 12], t3i = xi[j + 4] - xi[j + 12];
    float o0r = t0r + t2r, o0i = t0i + t2i;
    float o1r = t1r + t3i, o1i = t1i - t3r;   // t1 - i t3
    float o2r = t0r - t2r, o2i = t0i - t2i;
    float o3r = t1r - t3i, o3i = t1i + t3r;   // t1 + i t3
    yr[j] = o0r; yi[j] = o0i;
    if (j == 0) {
      yr[4] = o1r; yi[4] = o1i; yr[8] = o2r; yi[8] = o2i; yr[12] = o3r; yi[12] = o3i;
    } else {
      cmul(o1r, o1i, W16C[j], W16S[j], yr[j + 4], yi[j + 4]);
      cmul(o2r, o2i, W16C[2 * j], W16S[2 * j], yr[j + 8], yi[j + 8]);
      cmul(o3r, o3i, W16C[3 * j], W16S[3 * j], yr[j + 12], yi[j + 12]);
    }
  }
#pragma unroll
  for (int m = 0; m < 4; ++m) {
    float t0r = yr[4 * m] + yr[4 * m + 2],     t0i = yi[4 * m] + yi[4 * m + 2];
    float t1r = yr[4 * m] - yr[4 * m + 2],     t1i = yi[4 * m] - yi[4 * m + 2];
    float t2r = yr[4 * m + 1] + yr[4 * m + 3], t2i = yi[4 * m + 1] + yi[4 * m + 3];
    float t3r = yr[4 * m + 1] - yr[4 * m + 3], t3i = yi[4 * m + 1] - yi[4 * m + 3];
    xr[m] = t0r + t2r;       xi[m] = t0i + t2i;
    xr[m + 4] = t1r + t3i;   xi[m + 4] = t1i - t3r;
    xr[m + 8] = t0r - t2r;   xi[m + 8] = t0i - t2i;
    xr[m + 12] = t1r - t3i;  xi[m + 12] = t1i + t3r;
  }
}

// ---- inverse (unnormalized x16), natural-order in/out ----
__device__ __forceinline__ void ifft16_f(float* xr, float* xi) {
  float yr[16], yi[16];
#pragma unroll
  for (int m = 0; m < 4; ++m) {
    float t0r = xr[m] + xr[m + 8],      t0i = xi[m] + xi[m + 8];
    float t1r = xr[m] - xr[m + 8],      t1i = xi[m] - xi[m + 8];
    float t2r = xr[m + 4] + xr[m + 12], t2i = xi[m + 4] + xi[m + 12];
    float t3r = xr[m + 4] - xr[m + 12], t3i = xi[m + 4] - xi[m + 12];
    yr[4 * m] = t0r + t2r;     yi[4 * m] = t0i + t2i;
    yr[4 * m + 1] = t1r - t3i; yi[4 * m + 1] = t1i + t3r;  // t1 + i t3
    yr[4 * m + 2] = t0r - t2r; yi[4 * m + 2] = t0i - t2i;
    yr[4 * m + 3] = t1r + t3i; yi[4 * m + 3] = t1i - t3r;  // t1 - i t3
  }
#pragma unroll
  for (int j = 0; j < 4; ++j) {
    float v0r = yr[j], v0i = yi[j];
    float v1r, v1i, v2r, v2i, v3r, v3i;
    if (j == 0) {
      v1r = yr[4]; v1i = yi[4]; v2r = yr[8]; v2i = yi[8]; v3r = yr[12]; v3i = yi[12];
    } else {
      cmul(yr[j + 4], yi[j + 4], W16C[j], -W16S[j], v1r, v1i);
      cmul(yr[j + 8], yi[j + 8], W16C[2 * j], -W16S[2 * j], v2r, v2i);
      cmul(yr[j + 12], yi[j + 12], W16C[3 * j], -W16S[3 * j], v3r, v3i);
    }
    float t0r = v0r + v2r, t0i = v0i + v2i;
    float t1r = v0r - v2r, t1i = v0i - v2i;
    float t2r = v1r + v3r, t2i = v1i + v3i;
    float t3r = v1r - v3r, t3i = v1i - v3i;
    xr[j] = t0r + t2r;       xi[j] = t0i + t2i;
    xr[j + 4] = t1r - t3i;   xi[j + 4] = t1i + t3r;
    xr[j + 8] = t0r - t2r;   xi[j + 8] = t0i - t2i;
    xr[j + 12] = t1r + t3i;  xi[j + 12] = t1i - t3r;
  }
}

// twiddle powers w^m, m in [0,16), via depth-4 product tree (not a serial chain)
__device__ __forceinline__ void twtree(float ang, float* wc, float* ws) {
  wc[0] = 1.f; ws[0] = 0.f;
  __sincosf(ang, &ws[1], &wc[1]);
  cmul(wc[1], ws[1], wc[1], ws[1], wc[2], ws[2]);
  cmul(wc[1], ws[1], wc[2], ws[2], wc[3], ws[3]);
  cmul(wc[2], ws[2], wc[2], ws[2], wc[4], ws[4]);
  cmul(wc[1], ws[1], wc[4], ws[4], wc[5], ws[5]);
  cmul(wc[2], ws[2], wc[4], ws[4], wc[6], ws[6]);
  cmul(wc[3], ws[3], wc[4], ws[4], wc[7], ws[7]);
  cmul(wc[4], ws[4], wc[4], ws[4], wc[8], ws[8]);
#pragma unroll
  for (int m = 9; m < 16; ++m)
    cmul(wc[m - 8], ws[m - 8], wc[8], ws[8], wc[m], ws[m]);
}

// XOR-swizzle on float index (bank spread for contiguous-per-thread b128 ops)
__device__ __forceinline__ int swzf(int i) {
  return i ^ (((i >> 5) & 7) << 2);
}

__device__ __forceinline__ float gelu_exact(float y) {
  return 0.5f * y * (1.f + erff(y * 0.70710678118654752f));
}

// -------- pass 0: Wout fp32 -> bf16 ----------------------------------------
__global__ void wconv_kernel(const float* __restrict__ W,
                             __hip_bfloat16* __restrict__ Wb) {
  int i = blockIdx.x * 256 + threadIdx.x;
  Wb[i] = __float2bfloat16(W[i]);
}

// -------- pass 1: squash kernel + scrambled spectrum (x 1/N) ---------------
// Net: P1 radix-16 (q=512), P2 radix-16 (q=32), P3 radix-2+DFT16 (pairs).
__global__ __launch_bounds__(512, 4) void kf_kernel(const float* __restrict__ kern,
                                                    float* __restrict__ Kf) {
  __shared__ __align__(16) float sre[NFFT];
  __shared__ __align__(16) float sim[NFFT];
  const int t = threadIdx.x;
  const int h = blockIdx.x;
  const float* kr = kern + (size_t)h * LL;

  // P1
  {
    const int j = t;
    float xr[16], xi[16];
#pragma unroll
    for (int r = 0; r < 8; ++r) {
      float kv = kr[j + 512 * r];
      float a = fabsf(kv) - LAM;
      float sq = (a > 0.f) ? ((kv > 0.f) ? a : -a) : 0.f;
      xr[r] = sq * (1.0f / (float)NFFT);
      xi[r] = 0.f;
    }
#pragma unroll
    for (int r = 8; r < 16; ++r) { xr[r] = 0.f; xi[r] = 0.f; }
    fft16_f(xr, xi);
    float wc[16], ws[16];
    twtree(-6.283185307179586f * (float)j * (1.f / 8192.f), wc, ws);
    const int jx = j ^ (((j >> 5) & 7) << 2);
#pragma unroll
    for (int m = 0; m < 16; ++m) {
      float tr, ti; cmul(xr[m], xi[m], wc[m], ws[m], tr, ti);
      sre[jx + 512 * m] = tr; sim[jx + 512 * m] = ti;
    }
  }
  __syncthreads();

  // P2
  {
    const int jj = t & 31, gg = t >> 5;
    const int base = gg * 512 + jj;
    float xr[16], xi[16];
#pragma unroll
    for (int m = 0; m < 16; ++m) {
      const int a = (base + 32 * m) ^ ((m & 7) << 2);
      xr[m] = sre[a]; xi[m] = sim[a];
    }
    fft16_f(xr, xi);
    float wc[16], ws[16];
    twtree(-6.283185307179586f * (float)jj * (1.f / 512.f), wc, ws);
#pragma unroll
    for (int m = 0; m < 16; ++m) {
      const int a = (base + 32 * m) ^ ((m & 7) << 2);
      float tr, ti; cmul(xr[m], xi[m], wc[m], ws[m], tr, ti);
      sre[a] = tr; sim[a] = ti;
    }
  }
  __syncthreads();

  // P3: block k=t>>1 of 32 contiguous; radix-2 split (par=t&1) + DFT16
  {
    const int k = t >> 1, par = t & 1;
    const int kx = k & 7;
    const float sgn = par ? -1.f : 1.f;
    float xr[16], xi[16];
#pragma unroll
    for (int c = 0; c < 4; ++c) {
      float4 lr = ((const float4*)sre)[8 * k + (c ^ kx)];
      float4 hr = ((const float4*)sre)[8 * k + ((c + 4) ^ kx)];
      float4 li = ((const float4*)sim)[8 * k + (c ^ kx)];
      float4 hi4 = ((const float4*)sim)[8 * k + ((c + 4) ^ kx)];
      float vr[4] = {lr.x + sgn * hr.x, lr.y + sgn * hr.y, lr.z + sgn * hr.z, lr.w + sgn * hr.w};
      float vi[4] = {li.x + sgn * hi4.x, li.y + sgn * hi4.y, li.z + sgn * hi4.z, li.w + sgn * hi4.w};
#pragma unroll
      for (int e = 0; e < 4; ++e) {
        const int j = 4 * c + e;
        const float twr = par ? W32C[j] : 1.f;
        const float tws = par ? W32S[j] : 0.f;
        cmul(vr[e], vi[e], twr, tws, xr[j], xi[j]);
      }
    }
    fft16_f(xr, xi);
    float4* out4 = (float4*)(Kf + (size_t)h * NFFT * 2) + 8 * t;
#pragma unroll
    for (int c = 0; c < 8; ++c)
      out4[c] = make_float4(xr[2 * c], xi[2 * c], xr[2 * c + 1], xi[2 * c + 1]);
  }
}

// -------- pass 2: FFT conv (h, batch-pair) + skip + GELU -> g bf16 ---------
__global__ __launch_bounds__(512, 4) void fftconv_kernel(
    const float* __restrict__ u, const float* __restrict__ D,
    const float* __restrict__ Kf, __hip_bfloat16* __restrict__ g) {
  __shared__ __align__(16) float sre[NFFT];
  __shared__ __align__(16) float sim[NFFT];
  const int t = threadIdx.x;
  const int p = blockIdx.x;   // batch pair 0..7
  const int h = blockIdx.y;   // 0..511
  const int b0 = 2 * p, b1 = 2 * p + 1;
  const float* u0 = u + ((size_t)(b0 * HH + h)) * LL;
  const float* u1 = u + ((size_t)(b1 * HH + h)) * LL;

  float us0[8], us1[8];  // register stash of u for the epilogue
  const int jx = t ^ (((t >> 5) & 7) << 2);

  // ---- P1: radix-16, q=512, z = u0 + i*u1 ----
  {
    const int j = t;
    float xr[16], xi[16];
#pragma unroll
    for (int r = 0; r < 8; ++r) {
      float a = u0[j + 512 * r];
      float b = u1[j + 512 * r];
      us0[r] = a; us1[r] = b;
      xr[r] = a; xi[r] = b;
    }
#pragma unroll
    for (int r = 8; r < 16; ++r) { xr[r] = 0.f; xi[r] = 0.f; }
    fft16_f(xr, xi);
    float wc[16], ws[16];
    twtree(-6.283185307179586f * (float)j * (1.f / 8192.f), wc, ws);
#pragma unroll
    for (int m = 0; m < 16; ++m) {
      float tr, ti; cmul(xr[m], xi[m], wc[m], ws[m], tr, ti);
      sre[jx + 512 * m] = tr; sim[jx + 512 * m] = ti;
    }
  }
  __syncthreads();

  // ---- P2: radix-16, q=32 ----
  {
    const int jj = t & 31, gg = t >> 5;
    const int base = gg * 512 + jj;
    float xr[16], xi[16];
#pragma unroll
    for (int m = 0; m < 16; ++m) {
      const int a = (base + 32 * m) ^ ((m & 7) << 2);
      xr[m] = sre[a]; xi[m] = sim[a];
    }
    fft16_f(xr, xi);
    float wc[16], ws[16];
    twtree(-6.283185307179586f * (float)jj * (1.f / 512.f), wc, ws);
#pragma unroll
    for (int m = 0; m < 16; ++m) {
      const int a = (base + 32 * m) ^ ((m & 7) << 2);
      float tr, ti; cmul(xr[m], xi[m], wc[m], ws[m], tr, ti);
      sre[a] = tr; sim[a] = ti;
    }
  }
  __syncthreads();

  // ---- P3: radix-2 split + DFT16 + spectral mul + iDFT16 + inv radix-2 ----
  {
    const int k = t >> 1, par = t & 1;
    const int kx = k & 7;
    const float sgn = par ? -1.f : 1.f;
    float xr[16], xi[16];
#pragma unroll
    for (int c = 0; c < 4; ++c) {
      float4 lr = ((const float4*)sre)[8 * k + (c ^ kx)];
      float4 hr = ((const float4*)sre)[8 * k + ((c + 4) ^ kx)];
      float4 li = ((const float4*)sim)[8 * k + (c ^ kx)];
      float4 hi4 = ((const float4*)sim)[8 * k + ((c + 4) ^ kx)];
      float vr[4] = {lr.x + sgn * hr.x, lr.y + sgn * hr.y, lr.z + sgn * hr.z, lr.w + sgn * hr.w};
      float vi[4] = {li.x + sgn * hi4.x, li.y + sgn * hi4.y, li.z + sgn * hi4.z, li.w + sgn * hi4.w};
#pragma unroll
      for (int e = 0; e < 4; ++e) {
        const int j = 4 * c + e;
        const float twr = par ? W32C[j] : 1.f;
        const float tws = par ? W32S[j] : 0.f;
        cmul(vr[e], vi[e], twr, tws, xr[j], xi[j]);
      }
    }
    fft16_f(xr, xi);
    const float4* kf4 = (const float4*)(Kf + (size_t)h * NFFT * 2) + 8 * t;
#pragma unroll
    for (int c = 0; c < 8; ++c) {
      float4 kk = kf4[c];
      float tr, ti;
      cmul(xr[2 * c], xi[2 * c], kk.x, kk.y, tr, ti);
      xr[2 * c] = tr; xi[2 * c] = ti;
      cmul(xr[2 * c + 1], xi[2 * c + 1], kk.z, kk.w, tr, ti);
      xr[2 * c + 1] = tr; xi[2 * c + 1] = ti;
    }
    ifft16_f(xr, xi);
    // inverse radix-2 across the thread pair: even sends a~, odd sends conj(W)*b~
    float outr[16], outi[16];
#pragma unroll
    for (int j = 0; j < 16; ++j) {
      float pr, pi;
      if (par) cmul(xr[j], xi[j], W32C[j], -W32S[j], pr, pi);
      else { pr = xr[j]; pi = xi[j]; }
      float qr = __shfl_xor(pr, 1);
      float qi = __shfl_xor(pi, 1);
      outr[j] = par ? (qr - pr) : (pr + qr);
      outi[j] = par ? (qi - pi) : (pi + qi);
    }
#pragma unroll
    for (int c = 0; c < 4; ++c) {
      const int q = (4 * par + c) ^ kx;
      ((float4*)sre)[8 * k + q] = make_float4(outr[4 * c], outr[4 * c + 1], outr[4 * c + 2], outr[4 * c + 3]);
      ((float4*)sim)[8 * k + q] = make_float4(outi[4 * c], outi[4 * c + 1], outi[4 * c + 2], outi[4 * c + 3]);
    }
  }
  __syncthreads();

  // ---- P2' ----
  {
    const int jj = t & 31, gg = t >> 5;
    const int base = gg * 512 + jj;
    float wc[16], ws[16];
    twtree(6.283185307179586f * (float)jj * (1.f / 512.f), wc, ws);  // conj
    float yr[16], yi[16];
#pragma unroll
    for (int m = 0; m < 16; ++m) {
      const int a = (base + 32 * m) ^ ((m & 7) << 2);
      cmul(sre[a], sim[a], wc[m], ws[m], yr[m], yi[m]);
    }
    ifft16_f(yr, yi);
#pragma unroll
    for (int m = 0; m < 16; ++m) {
      const int a = (base + 32 * m) ^ ((m & 7) << 2);
      sre[a] = yr[m]; sim[a] = yi[m];
    }
  }
  __syncthreads();

  // ---- P1' + epilogue (skip + GELU -> bf16) ----
  {
    const int j = t;
    float wc[16], ws[16];
    twtree(6.283185307179586f * (float)j * (1.f / 8192.f), wc, ws);  // conj
    float yr[16], yi[16];
#pragma unroll
    for (int m = 0; m < 16; ++m) {
      cmul(sre[jx + 512 * m], sim[jx + 512 * m], wc[m], ws[m], yr[m], yi[m]);
    }
    ifft16_f(yr, yi);
    const float Dh = D[h];
    __hip_bfloat16* g0 = g + ((size_t)(b0 * HH + h)) * LL;
    __hip_bfloat16* g1 = g + ((size_t)(b1 * HH + h)) * LL;
#pragma unroll
    for (int r = 0; r < 8; ++r) {
      float y0 = yr[r] + Dh * us0[r];
      float y1 = yi[r] + Dh * us1[r];
      g0[j + 512 * r] = __float2bfloat16(gelu_exact(y0));
      g1[j + 512 * r] = __float2bfloat16(gelu_exact(y1));
    }
  }
}

// -------- pass 2.5: transpose g[b][h][l] -> g2[b][l][h] (bf16) -------------
__global__ __launch_bounds__(256) void transpose_kernel(
    const __hip_bfloat16* __restrict__ g, __hip_bfloat16* __restrict__ g2) {
  __shared__ unsigned short tile[64][72];
  const int lb = blockIdx.x;
  const int hb = blockIdx.y;
  const int b = blockIdx.z;
  const int l0 = lb * 64, h0 = hb * 64;
  const int tid = threadIdx.x;
  const int r = tid >> 3;
  const int c = (tid & 7) * 8;
  const unsigned short* gs = (const unsigned short*)g;
  unsigned short* g2s = (unsigned short*)g2;
  for (int it = 0; it < 2; ++it) {
    int rr = r + it * 32;
    int4 v = *(const int4*)(gs + ((size_t)(b * HH + h0 + rr)) * LL + l0 + c);
    *(int4*)&tile[rr][c] = v;
  }
  __syncthreads();
  for (int it = 0; it < 2; ++it) {
    int rr = r + it * 32;
    unsigned short vals[8];
#pragma unroll
    for (int j = 0; j < 8; ++j) vals[j] = tile[c + j][rr];
    *(int4*)(g2s + ((size_t)(b * LL + l0 + rr)) * HH + h0 + c) = *(int4*)vals;
  }
}

// -------- pass 3: out[b][v][l] = silu(sum_h W[v][h]*g2[b][l][h] + bout[v]) -
// grid = (vt, lt, b) with vt fastest so the 4 blocks sharing a g2-tile are
// dispatch-adjacent (L2 reuse of the 131 KB B-tile).
__global__ __launch_bounds__(256, 4) void gemm_kernel(
    const __hip_bfloat16* __restrict__ Wb, const __hip_bfloat16* __restrict__ g2,
    const float* __restrict__ bout, float* __restrict__ out) {
  const int vt = blockIdx.x;  // 0..3
  const int lt = blockIdx.y;  // 0..31
  const int b = blockIdx.z;
  const int wave = threadIdx.x >> 6;
  const int ln = threadIdx.x & 63;
  const int wr = wave >> 1, wc = wave & 1;
  const int vbase = vt * 128 + wr * 64;
  const int lbase = lt * 128 + wc * 64;
  const int lane16 = ln & 15;
  const int quad = ln >> 4;

  floatx4 acc[4][4];
#pragma unroll
  for (int mi = 0; mi < 4; ++mi)
#pragma unroll
    for (int ni = 0; ni < 4; ++ni) acc[mi][ni] = (floatx4){0.f, 0.f, 0.f, 0.f};

  const unsigned short* A = (const unsigned short*)Wb;
  const unsigned short* Bm = (const unsigned short*)g2 + (size_t)b * LL * HH;

  for (int k0 = 0; k0 < HH; k0 += 32) {
    const int kk = k0 + quad * 8;
    short8 af[4], bf[4];
#pragma unroll
    for (int mi = 0; mi < 4; ++mi) {
      const int m = vbase + mi * 16 + lane16;
      af[mi] = *(const short8*)(A + (size_t)m * HH + kk);
    }
#pragma unroll
    for (int ni = 0; ni < 4; ++ni) {
      const int n = lbase + ni * 16 + lane16;
      bf[ni] = *(const short8*)(Bm + (size_t)n * HH + kk);
    }
#pragma unroll
    for (int mi = 0; mi < 4; ++mi)
#pragma unroll
      for (int ni = 0; ni < 4; ++ni)
        acc[mi][ni] = __builtin_amdgcn_mfma_f32_16x16x32_bf16(af[mi], bf[ni],
                                                              acc[mi][ni], 0, 0, 0);
  }

#pragma unroll
  for (int mi = 0; mi < 4; ++mi) {
#pragma unroll
    for (int r = 0; r < 4; ++r) {
      const int m = vbase + mi * 16 + quad * 4 + r;
      const float bias = bout[m];
#pragma unroll
      for (int ni = 0; ni < 4; ++ni) {
        const int n = lbase + ni * 16 + lane16;
        float y = acc[mi][ni][r] + bias;
        y = y / (1.f + __expf(-y));
        out[((size_t)(b * HH + m)) * LL + n] = y;
      }
    }
  }
}

extern "C" void kernel_launch(void* const* d_in, const int* in_sizes, int n_in,
                              void* d_out, int out_size, void* d_ws, size_t ws_size,
                              hipStream_t stream) {
  const float* u = (const float*)d_in[0];
  const float* kern = (const float*)d_in[1];
  const float* D = (const float*)d_in[2];
  const float* Wout = (const float*)d_in[3];
  const float* bout = (const float*)d_in[4];
  float* out = (float*)d_out;

  char* ws = (char*)d_ws;
  const size_t KF_BYTES = (size_t)HH * NFFT * sizeof(float2);
  const size_t G_BYTES = (size_t)BB * HH * LL * 2;
  float* Kf = (float*)ws;  // interleaved (re,im) pairs, scrambled order
  __hip_bfloat16* g = (__hip_bfloat16*)(ws + KF_BYTES);
  __hip_bfloat16* g2 = (__hip_bfloat16*)(ws + KF_BYTES + G_BYTES);
  __hip_bfloat16* Wb = (__hip_bfloat16*)(ws + KF_BYTES + 2 * G_BYTES);

  wconv_kernel<<<dim3((HH * HH) / 256), dim3(256), 0, stream>>>(Wout, Wb);
  kf_kernel<<<dim3(HH), dim3(512), 0, stream>>>(kern, Kf);
  fftconv_kernel<<<dim3(BB / 2, HH), dim3(512), 0, stream>>>(u, D, Kf, g);
  transpose_kernel<<<dim3(LL / 64, HH / 64, BB), dim3(256), 0, stream>>>(g, g2);
  gemm_kernel<<<dim3(HH / 128, LL / 128, BB), dim3(256), 0, stream>>>(Wb, g2, bout, out);
}